// Round 4
// baseline (958.831 us; speedup 1.0000x reference)
//
#include <hip/hip_runtime.h>

#define NNODES 262144
#define NSEG   1024
#define DIN    512
#define NB     64                 // nodes per k_main block
#define NBLK   (NNODES / NB)      // 4096

typedef __attribute__((ext_vector_type(8))) short bf16x8;
typedef __attribute__((ext_vector_type(4))) float f32x4;

__device__ __forceinline__ unsigned short f2bf(float f){
  unsigned u = __float_as_uint(f);
  u += 0x7FFFu + ((u >> 16) & 1u);
  return (unsigned short)(u >> 16);
}

__device__ __forceinline__ float tanh_fast(float v){
  float z = fminf(fmaxf(v, -15.f), 15.f);
  float e = __expf(2.f * z);
  return (e - 1.f) / (e + 1.f);
}

__device__ __forceinline__ void atomic_addf(float* p, float v){
  __hip_atomic_fetch_add(p, v, __ATOMIC_RELAXED, __HIP_MEMORY_SCOPE_AGENT);
}

// ---- prep: wbt bf16 [16 ks][256 hk][32 k], zero pooled + zsum ----
__global__ __launch_bounds__(256)
void k_prep(const float* __restrict__ wh,
            unsigned short* __restrict__ wbt,
            float4* __restrict__ pooled4, float4* __restrict__ zsum4){
  int g = blockIdx.x * 256 + threadIdx.x;
  if (g < 131072){
    int ks = g >> 13, rem = g & 8191, hk = rem >> 5, kl = rem & 31;
    wbt[g] = f2bf(wh[hk * DIN + ks * 32 + kl]);
  } else if (g < 131072 + 524288){
    pooled4[g - 131072] = (float4){0.f, 0.f, 0.f, 0.f};
  } else if (g < 131072 + 524288 + 1024){
    zsum4[g - 131072 - 524288] = (float4){0.f, 0.f, 0.f, 0.f};
  }
}

// ---- fused: scores (bf16 MFMA) -> exp -> segment pool (atomics) ----
__global__ __launch_bounds__(256)
void k_main(const float* __restrict__ x, const unsigned short* __restrict__ wbt,
            const float* __restrict__ bh, const float* __restrict__ ctx,
            const int* __restrict__ batch, float* __restrict__ pooled,
            float* __restrict__ zsum){
  __shared__ __align__(16) unsigned short xs[NB * DIN];   // 64 KB, XOR-swizzled
  __shared__ __align__(16) float wl[NB][4];               // exp(score) per node/head
  __shared__ int bcache[NB];
  const int t = threadIdx.x, w = t >> 6, l = t & 63;
  const int nb = blockIdx.x * NB;

  // ---- stage x tile (64 x 512 f32) -> bf16 LDS, swizzle byte ^= (row&7)<<4 ----
  const float4* xp = (const float4*)(x + (size_t)nb * DIN);
#pragma unroll 8
  for (int i = 0; i < 32; ++i){
    float4 v = xp[i * 256 + t];
    int flat = (i * 256 + t) * 4;
    int row = flat >> 9, col = flat & 511;
    unsigned lo = (unsigned)f2bf(v.x) | ((unsigned)f2bf(v.y) << 16);
    unsigned hi = (unsigned)f2bf(v.z) | ((unsigned)f2bf(v.w) << 16);
    int byte = (row << 10) + (col << 1);
    byte ^= (row & 7) << 4;
    *(uint2*)((char*)xs + byte) = make_uint2(lo, hi);
  }
  if (t < NB) bcache[t] = batch[nb + t];

  // per-lane head params: wave w == head w (hk = (w*4+q)*16 + (l&15))
  const int fr = l & 15, fc8 = (l >> 4) * 8;
  float bhv[4], cxv[4];
#pragma unroll
  for (int q = 0; q < 4; ++q){
    int hk = (w * 4 + q) * 16 + fr;
    bhv[q] = bh[hk];
    cxv[q] = ctx[hk];
  }

  // B fragment prologue (global->reg, L2-resident wbt, coalesced)
  bf16x8 Ba[4], Bb[4];
#pragma unroll
  for (int q = 0; q < 4; ++q)
    Ba[q] = *(const bf16x8*)(wbt + ((w * 4 + q) * 16 + fr) * 32 + fc8);

  f32x4 acc[4][4];
#pragma unroll
  for (int nt = 0; nt < 4; ++nt)
#pragma unroll
    for (int q = 0; q < 4; ++q) acc[nt][q] = (f32x4){0.f, 0.f, 0.f, 0.f};

  __syncthreads();

  const int fcb = (l >> 4) * 16;     // frag col byte offset within kstep chunk
#pragma unroll
  for (int ks2 = 0; ks2 < 16; ks2 += 2){
    {  // prefetch B for ks2+1
      const unsigned short* wp = wbt + (ks2 + 1) * 8192;
#pragma unroll
      for (int q = 0; q < 4; ++q)
        Bb[q] = *(const bf16x8*)(wp + ((w * 4 + q) * 16 + fr) * 32 + fc8);
    }
    {  // compute ks2
      bf16x8 A[4];
#pragma unroll
      for (int nt = 0; nt < 4; ++nt){
        int b = ((nt * 16 + fr) << 10) + (ks2 << 6) + fcb;
        b ^= (fr & 7) << 4;
        A[nt] = *(const bf16x8*)((const char*)xs + b);
      }
#pragma unroll
      for (int nt = 0; nt < 4; ++nt)
#pragma unroll
        for (int q = 0; q < 4; ++q)
          acc[nt][q] = __builtin_amdgcn_mfma_f32_16x16x32_bf16(A[nt], Ba[q], acc[nt][q], 0, 0, 0);
    }
    if (ks2 + 2 < 16){  // prefetch B for ks2+2
      const unsigned short* wp = wbt + (ks2 + 2) * 8192;
#pragma unroll
      for (int q = 0; q < 4; ++q)
        Ba[q] = *(const bf16x8*)(wp + ((w * 4 + q) * 16 + fr) * 32 + fc8);
    }
    {  // compute ks2+1
      bf16x8 A[4];
#pragma unroll
      for (int nt = 0; nt < 4; ++nt){
        int b = ((nt * 16 + fr) << 10) + ((ks2 + 1) << 6) + fcb;
        b ^= (fr & 7) << 4;
        A[nt] = *(const bf16x8*)((const char*)xs + b);
      }
#pragma unroll
      for (int nt = 0; nt < 4; ++nt)
#pragma unroll
        for (int q = 0; q < 4; ++q)
          acc[nt][q] = __builtin_amdgcn_mfma_f32_16x16x32_bf16(A[nt], Bb[q], acc[nt][q], 0, 0, 0);
    }
  }

  // ---- epilogue: score -> exp weights in LDS ----
#pragma unroll
  for (int nt = 0; nt < 4; ++nt){
#pragma unroll
    for (int r = 0; r < 4; ++r){
      float s = 0.f;
#pragma unroll
      for (int q = 0; q < 4; ++q)
        s += tanh_fast(acc[nt][q][r] + bhv[q]) * cxv[q];
#pragma unroll
      for (int off = 1; off < 16; off <<= 1)
        s += __shfl_xor(s, off);
      if (fr == 0)
        wl[nt * 16 + (l >> 4) * 4 + r][w] = __expf(s);
    }
  }
  __syncthreads();

  // ---- pool phase: thread owns cols 2t,2t+1; flush per segment run ----
  float2 a0 = {0.f,0.f}, a1 = {0.f,0.f}, a2 = {0.f,0.f}, a3 = {0.f,0.f};
  int cur = bcache[0], run0 = 0;

  for (int n = 0; n < NB; ++n){
    int sg = bcache[n];
    if (sg != cur){                    // uniform branch across block
      float* base = pooled + (size_t)cur * 2048 + 2 * t;
      atomic_addf(base + 0,      a0.x); atomic_addf(base + 1,      a0.y);
      atomic_addf(base + 512,    a1.x); atomic_addf(base + 513,    a1.y);
      atomic_addf(base + 1024,   a2.x); atomic_addf(base + 1025,   a2.y);
      atomic_addf(base + 1536,   a3.x); atomic_addf(base + 1537,   a3.y);
      if (t < 64){
        int h = t & 3, i0 = t >> 2;
        float zs = 0.f;
        for (int m = run0 + i0; m < n; m += 16) zs += wl[m][h];
        zs += __shfl_xor(zs, 4);  zs += __shfl_xor(zs, 8);
        zs += __shfl_xor(zs, 16); zs += __shfl_xor(zs, 32);
        if (t < 4) atomic_addf(zsum + cur * 4 + t, zs);
      }
      a0 = a1 = a2 = a3 = (float2){0.f, 0.f};
      cur = sg; run0 = n;
    }
    int byte = (n << 10) + (t << 2);
    byte ^= (n & 7) << 4;
    unsigned xv = *(const unsigned*)((const char*)xs + byte);
    float x0 = __uint_as_float(xv << 16);
    float x1 = __uint_as_float(xv & 0xFFFF0000u);
    float4 wv = *(const float4*)&wl[n][0];
    a0.x += wv.x * x0; a0.y += wv.x * x1;
    a1.x += wv.y * x0; a1.y += wv.y * x1;
    a2.x += wv.z * x0; a2.y += wv.z * x1;
    a3.x += wv.w * x0; a3.y += wv.w * x1;
  }
  {
    float* base = pooled + (size_t)cur * 2048 + 2 * t;
    atomic_addf(base + 0,      a0.x); atomic_addf(base + 1,      a0.y);
    atomic_addf(base + 512,    a1.x); atomic_addf(base + 513,    a1.y);
    atomic_addf(base + 1024,   a2.x); atomic_addf(base + 1025,   a2.y);
    atomic_addf(base + 1536,   a3.x); atomic_addf(base + 1537,   a3.y);
    if (t < 64){
      int h = t & 3, i0 = t >> 2;
      float zs = 0.f;
      for (int m = run0 + i0; m < NB; m += 16) zs += wl[m][h];
      zs += __shfl_xor(zs, 4);  zs += __shfl_xor(zs, 8);
      zs += __shfl_xor(zs, 16); zs += __shfl_xor(zs, 32);
      if (t < 4) atomic_addf(zsum + cur * 4 + t, zs);
    }
  }
}

// ---- out: normalize pooled by Z, GEMM [1024x2048]x[2048x512]^T(Wc) + bias ----
__global__ __launch_bounds__(256)
void k_out(const float* __restrict__ pooled, const float* __restrict__ wc,
           const float* __restrict__ zsum, const float* __restrict__ bias,
           float* __restrict__ out){
  __shared__ float ps[16][32];     // pooled tile (normalized)
  __shared__ float wt[32][65];     // Wc tile, padded (wt[jj][cc] = Wc[c0+cc][j0+jj])
  __shared__ float rz[16][4];
  const int t = threadIdx.x;
  const int br = blockIdx.x >> 3, bc = blockIdx.x & 7;
  const int r0 = br * 16, c0 = bc * 64;
  if (t < 64){
    int row = t >> 2, h = t & 3;
    float z = zsum[(r0 + row) * 4 + h];
    rz[row][h] = (z > 0.f) ? 1.f / z : 0.f;
  }
  __syncthreads();

  const int w4 = t >> 6, col = t & 63;
  float acc[4] = {0.f, 0.f, 0.f, 0.f};

  for (int j0 = 0; j0 < 2048; j0 += 32){
    int h0 = j0 >> 9;
#pragma unroll
    for (int i = 0; i < 2; ++i){            // ps tile: 512 elems
      int e = i * 256 + t;
      int row = e >> 5, jj = e & 31;
      ps[row][jj] = pooled[(size_t)(r0 + row) * 2048 + j0 + jj] * rz[row][h0];
    }
#pragma unroll
    for (int i = 0; i < 8; ++i){            // Wc tile: 2048 elems, j-contiguous reads
      int e = i * 256 + t;
      int jj = e & 31, cc = e >> 5;
      wt[jj][cc] = wc[(size_t)(c0 + cc) * 2048 + j0 + jj];
    }
    __syncthreads();
#pragma unroll 8
    for (int jj = 0; jj < 32; ++jj){
      float wv = wt[jj][col];
#pragma unroll
      for (int i = 0; i < 4; ++i)
        acc[i] += ps[w4 * 4 + i][jj] * wv;
    }
    __syncthreads();
  }
  float bv = bias[c0 + col];
#pragma unroll
  for (int i = 0; i < 4; ++i)
    out[(size_t)(r0 + w4 * 4 + i) * 512 + c0 + col] = acc[i] + bv;
}

extern "C" void kernel_launch(void* const* d_in, const int* in_sizes, int n_in,
                              void* d_out, int out_size, void* d_ws, size_t ws_size,
                              hipStream_t stream){
  const float* x     = (const float*)d_in[0];
  const int*   batch = (const int*)d_in[1];
  const float* Wh    = (const float*)d_in[2];
  const float* bh    = (const float*)d_in[3];
  const float* ctx   = (const float*)d_in[4];
  const float* Wc    = (const float*)d_in[5];
  const float* bcv   = (const float*)d_in[6];
  float* out = (float*)d_out;

  char* ws = (char*)d_ws;
  unsigned short* wbt = (unsigned short*)(ws + 0);        // 256 KB  [16][256][32] bf16
  float* pooled       = (float*)(ws + 262144);            // 8 MB    [1024][4][512]
  float* zsum         = (float*)(ws + 8650752);           // 16 KB   [1024][4]

  k_prep<<<2564, 256, 0, stream>>>(Wh, wbt, (float4*)pooled, (float4*)zsum);
  k_main<<<NBLK, 256, 0, stream>>>(x, wbt, bh, ctx, batch, pooled, zsum);
  k_out <<<512, 256, 0, stream>>>(pooled, Wc, zsum, bcv, out);
}